// Round 23
// baseline (139.629 us; speedup 1.0000x reference)
//
#include <hip/hip_runtime.h>
#include <hip/hip_bf16.h>
#include <cstdint>
#include <cstddef>

// Spatiotemporal dual-softmax attention, MI355X (gfx950).
// B=4, C=64, CI=32, N=H*W=4096. Flash-style, never materializes the 4096^2
// energy matrix. Round-23 = round-22 (direct-from-global fragments, L2-
// resident via XCD swizzle: FETCH 7.2MB, conflicts ~0 -- but 200cy L2
// latency landed on the chunk critical path) + 2-DEEP REGISTER PREFETCH:
// flattened 32-chunk loop, unrolled x2 with explicit A/B fragment register
// sets; next chunk's 4 coalesced loads issue before computing the current
// chunk (~250cy compute covers ~200cy L2 latency). No barriers, no LDS, no
// staging VALU in the main loop. Fragment addressing byte-identical to r22.
//   proj  (512 blk x 512): MFMA projections; g written in paired-chunk layout.
//   apply (512 blk x 512): XCD-aware remap, 8 waves = 2 rg x 4 cg.
//         Energy MFMA (swapped operands) -> exp2 (theta pre-scaled by log2e;
//         energies provably << 80, no max subtraction) -> bf16 pack ->
//         K=32 PV MFMA + ones-MFMA row sums; s_setprio(1) around compute.
//         Epilogue: 4-way cg combine, normalize, output conv+BN+residual.

#define B_  4
#define C_  64
#define CI_ 32
#define N_  4096
static constexpr float EPS_   = 1e-5f;
static constexpr float LOG2E_ = 1.4426950408889634f;

typedef __attribute__((ext_vector_type(8))) short  short8;
typedef __attribute__((ext_vector_type(4))) short  short4v;
typedef __attribute__((ext_vector_type(4))) float  float4v;
typedef __attribute__((ext_vector_type(8))) __bf16 bf16x8;

__device__ __forceinline__ short f2bf(float f) {
    unsigned u = __float_as_uint(f);
    unsigned r = (u + 0x7fffu + ((u >> 16) & 1u)) >> 16;   // RNE
    return (short)r;
}

// ---------------------------------------------------------------------------
// MFMA projections (identical to r22, which passed). side = blk>>8:
// 0: x1 -> {theta*log2e, g1}; 1: x2 -> {phi, g2}. theta/phi: [b][n][32] frag
// layout; g: PAIRED-CHUNK layout [b][chunk=n>>5][ci][pos], pos =
// ((n>>2)&3)*8 + ((n>>4)&1)*4 + (n&3)  (one 16B load = PV A-fragment).
// ---------------------------------------------------------------------------
__global__ __launch_bounds__(512) void proj_kernel(
    const float* __restrict__ x1, const float* __restrict__ x2,
    const float* __restrict__ g_w, const float* __restrict__ g_b, const float* __restrict__ g_bn,
    const float* __restrict__ t_w, const float* __restrict__ t_b, const float* __restrict__ t_bn,
    const float* __restrict__ p_w, const float* __restrict__ p_b, const float* __restrict__ p_bn,
    short* __restrict__ th_t, short* __restrict__ ph_t,
    short* __restrict__ g1q, short* __restrict__ g2q)
{
    const int side = blockIdx.x >> 8;
    const int rb   = blockIdx.x & 255;
    const int b    = rb >> 6;
    const int n0   = (rb & 63) * 64;
    const int tid  = threadIdx.x;
    const int wv   = tid >> 6, lane = tid & 63;
    const int lg   = lane >> 4, lr = lane & 15;

    const float* x   = side ? x2   : x1;
    const float* wA  = side ? p_w  : t_w;
    const float* bA  = side ? p_b  : t_b;
    const float* bnA = side ? p_bn : t_bn;
    short* outA      = side ? ph_t : th_t;
    short* outG      = side ? g2q  : g1q;
    const float scaleA = side ? 1.0f : LOG2E_;   // theta carries log2e

    __shared__ short xs_t[64][72];      // 9216 B  X^T: [n][c] bf16 (pad 72)
    __shared__ short wfb[2][32][72];    // 9216 B  [set][o][c] bf16 (pad 72)
    __shared__ float bfold[2][CI_];

    for (int it = 0; it < 4; it++) {                 // fold both weight sets
        int idx = it * 512 + tid;                    // [o][c] flat, 2048
        int o = idx >> 6, c = idx & 63;
        float invA = bnA[c]  * rsqrtf(bnA[192 + c]  + EPS_);
        float invG = g_bn[c] * rsqrtf(g_bn[192 + c] + EPS_);
        wfb[0][o][c] = f2bf(wA[idx]  * invA * scaleA);
        wfb[1][o][c] = f2bf(g_w[idx] * invG);
    }
    if (tid < 2 * CI_) {
        int set = tid >> 5, o = tid & 31;
        const float* bn = set ? g_bn : bnA;
        const float* w  = set ? g_w  : wA;
        const float* bs = set ? g_b  : bA;
        float s = bs[o];
        for (int c = 0; c < C_; c++) {
            float inv = bn[c] * rsqrtf(bn[192 + c] + EPS_);
            s += w[o * C_ + c] * (bn[64 + c] - bn[128 + c] * inv);
        }
        bfold[set][o] = set ? s : s * scaleA;
    }
    const float* xb = x + (size_t)b * C_ * N_ + n0;
    for (int it = 0; it < 2; it++) {                 // stage X^T as bf16
        int idx = it * 512 + tid;                    // 1024 float4 pieces
        int c = idx >> 4, nq = idx & 15;
        float4 xv = *(const float4*)(xb + (size_t)c * N_ + nq * 4);
        xs_t[nq * 4 + 0][c] = f2bf(xv.x);
        xs_t[nq * 4 + 1][c] = f2bf(xv.y);
        xs_t[nq * 4 + 2][c] = f2bf(xv.z);
        xs_t[nq * 4 + 3][c] = f2bf(xv.w);
    }
    __syncthreads();

    const int set = wv & 1;              // 0 = theta/phi, 1 = g
    const int oT  = (wv >> 1) & 1;       // o tile: o = oT*16 + lg*4 + i
    const int nP  = wv >> 2;             // n pair: nTiles {2nP, 2nP+1}

    const float4v zero4 = {0.f, 0.f, 0.f, 0.f};
    // W A-frags (lane: A[row = oT*16+lr][k = c0 + lg*8 + j])
    short8 wf0 = *(const short8*)&wfb[set][oT * 16 + lr][lg * 8];
    short8 wf1 = *(const short8*)&wfb[set][oT * 16 + lr][32 + lg * 8];
    float4v cinit = zero4;
#pragma unroll
    for (int i = 0; i < 4; ++i) cinit[i] = bfold[set][oT * 16 + lg * 4 + i];

#pragma unroll
    for (int t = 0; t < 2; ++t) {
        const int nT = nP * 2 + t;
        // X B-frags (lane: B[k = c0 + lg*8 + j][col = nT*16 + lr])
        short8 xf0 = *(const short8*)&xs_t[nT * 16 + lr][lg * 8];
        short8 xf1 = *(const short8*)&xs_t[nT * 16 + lr][32 + lg * 8];
        float4v d = __builtin_amdgcn_mfma_f32_16x16x32_bf16(wf0, xf0, cinit, 0, 0, 0);
        d = __builtin_amdgcn_mfma_f32_16x16x32_bf16(wf1, xf1, d, 0, 0, 0);
        // d[i] = out[o = oT*16 + lg*4 + i][n = n0 + nT*16 + lr]
        const int n = n0 + nT * 16 + lr;
        if (set == 0) {
            short4v v;
#pragma unroll
            for (int i = 0; i < 4; ++i) v[i] = f2bf(d[i]);
            *(short4v*)(outA + ((size_t)b * N_ + n) * CI_ + oT * 16 + lg * 4) = v;
        } else {
            // paired-chunk: [chunk][ci][pos], chunk stride 1024 shorts,
            // ci stride 32 shorts
            const int pos = ((n >> 2) & 3) * 8 + ((n >> 4) & 1) * 4 + (n & 3);
            short* vq = outG + (size_t)b * CI_ * N_ + (size_t)(n >> 5) * 1024 + pos;
#pragma unroll
            for (int i = 0; i < 4; ++i)
                vq[(oT * 16 + lg * 4 + i) * 32] = f2bf(d[i]);
        }
    }
}

// ---------------------------------------------------------------------------
// Apply (fused softmax-sum + PV + output conv + residual).
// XCD-aware decode: grp = bid&7 -> (side,b) pinned to one XCD's L2.
// 8 waves = 2 rg x 4 cg; 32 flattened chunk-iterations, direct-from-global
// fragments with a 2-deep register prefetch pipeline (A/B sets). No
// main-loop LDS or barriers. PV + sums via K=32 MFMAs.
// ---------------------------------------------------------------------------
__global__ __launch_bounds__(512, 6) void apply_kernel(
    const short* __restrict__ th, const short* __restrict__ ph,
    const short* __restrict__ g1q, const short* __restrict__ g2q,
    const float* __restrict__ x1, const float* __restrict__ x2,
    const float* __restrict__ Ww, const float* __restrict__ Wb,
    const float* __restrict__ w_bn,
    float* __restrict__ out)
{
    const int bid  = blockIdx.x;
    const int grp  = bid & 7;               // (side,b) group -> XCD affinity
    const int side = grp >> 2;
    const int b    = grp & 3;
    const int r0   = (bid >> 3) * 64;
    const short* A  = side ? th : ph;       // rows = softmax/output dim (m)
    const short* Bm = side ? ph : th;       // cols = reduction dim (n)
    const short* V  = side ? g2q : g1q;     // paired-chunk layout
    const int tid = threadIdx.x;
    const int wv = tid >> 6, lane = tid & 63;
    const int cg = wv & 3, rg = wv >> 2;
    const int lg = lane >> 4, lr = lane & 15;

    // epilogue-only LDS (35584 B)
    __shared__ __align__(16) char smem[35584];
    float (*buf2)[64][33] = (float(*)[64][33])smem;            // 16896
    float (*sums)[64]     = (float(*)[64])(smem + 16896);      //  1024
    float (*ybuf)[36]     = (float(*)[36])(smem + 17920);      //  9216
    float (*wf2)[CI_]     = (float(*)[CI_])(smem + 27136);     //  8192
    float *bf2v           = (float*)(smem + 35328);            //   256

    const short* Ab = A  + (size_t)b * N_ * CI_;
    const short* Bb = Bm + (size_t)b * N_ * CI_;
    const short* Vb = V  + (size_t)b * CI_ * N_;

    short8 afrag0 = *(const short8*)(Ab + (size_t)(r0 + rg * 32 + lr) * CI_ + lg * 8);
    short8 afrag1 = *(const short8*)(Ab + (size_t)(r0 + rg * 32 + 16 + lr) * CI_ + lg * 8);

    short8 ones8;
#pragma unroll
    for (int i = 0; i < 8; ++i) ones8[i] = (short)0x3F80;    // bf16 1.0

    const float4v zero4 = {0.f, 0.f, 0.f, 0.f};
    float4v a00 = zero4, a01 = zero4;   // t=0: y[ci=4lg+i][m], y[16+4lg+i][m]
    float4v a10 = zero4, a11 = zero4;   // t=1 (m + 16)
    float4v sum0 = zero4, sum1 = zero4; // ones-MFMA sum accumulators

    // per-lane fragment bases
    const short* Bl0 = Bb + (size_t)lr * CI_ + lg * 8;          // + c*32
    const short* Bl1 = Bb + (size_t)(16 + lr) * CI_ + lg * 8;
    const short* Vl0 = Vb + (size_t)lr * 32 + lg * 8;           // + (c>>5)*1024
    const short* Vl1 = Vb + (size_t)(16 + lr) * 32 + lg * 8;

    // chunk index for flattened iteration: it = win*2 + ch2
    #define CIDX(it) (((it) >> 1) * 256 + ((it) & 1) * 128 + cg * 32)

    auto compute = [&](short8 b0, short8 b1, short8 vA0, short8 vA1) {
        __builtin_amdgcn_s_setprio(1);
        {   // t = 0 (m rows r0 + rg*32 + lr)
            float4v e0 = __builtin_amdgcn_mfma_f32_16x16x32_bf16(b0, afrag0, zero4, 0, 0, 0);
            float4v e1 = __builtin_amdgcn_mfma_f32_16x16x32_bf16(b1, afrag0, zero4, 0, 0, 0);
            float p0 = __builtin_amdgcn_exp2f(e0[0]), p1 = __builtin_amdgcn_exp2f(e0[1]);
            float p2 = __builtin_amdgcn_exp2f(e0[2]), p3 = __builtin_amdgcn_exp2f(e0[3]);
            float p4 = __builtin_amdgcn_exp2f(e1[0]), p5 = __builtin_amdgcn_exp2f(e1[1]);
            float p6 = __builtin_amdgcn_exp2f(e1[2]), p7 = __builtin_amdgcn_exp2f(e1[3]);
            bf16x8 q;
            q[0] = (__bf16)p0; q[1] = (__bf16)p1; q[2] = (__bf16)p2; q[3] = (__bf16)p3;
            q[4] = (__bf16)p4; q[5] = (__bf16)p5; q[6] = (__bf16)p6; q[7] = (__bf16)p7;
            short8 pk = __builtin_bit_cast(short8, q);
            a00  = __builtin_amdgcn_mfma_f32_16x16x32_bf16(vA0, pk, a00, 0, 0, 0);
            a01  = __builtin_amdgcn_mfma_f32_16x16x32_bf16(vA1, pk, a01, 0, 0, 0);
            sum0 = __builtin_amdgcn_mfma_f32_16x16x32_bf16(ones8, pk, sum0, 0, 0, 0);
        }
        {   // t = 1 (m rows r0 + rg*32 + 16 + lr)
            float4v e0 = __builtin_amdgcn_mfma_f32_16x16x32_bf16(b0, afrag1, zero4, 0, 0, 0);
            float4v e1 = __builtin_amdgcn_mfma_f32_16x16x32_bf16(b1, afrag1, zero4, 0, 0, 0);
            float p0 = __builtin_amdgcn_exp2f(e0[0]), p1 = __builtin_amdgcn_exp2f(e0[1]);
            float p2 = __builtin_amdgcn_exp2f(e0[2]), p3 = __builtin_amdgcn_exp2f(e0[3]);
            float p4 = __builtin_amdgcn_exp2f(e1[0]), p5 = __builtin_amdgcn_exp2f(e1[1]);
            float p6 = __builtin_amdgcn_exp2f(e1[2]), p7 = __builtin_amdgcn_exp2f(e1[3]);
            bf16x8 q;
            q[0] = (__bf16)p0; q[1] = (__bf16)p1; q[2] = (__bf16)p2; q[3] = (__bf16)p3;
            q[4] = (__bf16)p4; q[5] = (__bf16)p5; q[6] = (__bf16)p6; q[7] = (__bf16)p7;
            short8 pk = __builtin_bit_cast(short8, q);
            a10  = __builtin_amdgcn_mfma_f32_16x16x32_bf16(vA0, pk, a10, 0, 0, 0);
            a11  = __builtin_amdgcn_mfma_f32_16x16x32_bf16(vA1, pk, a11, 0, 0, 0);
            sum1 = __builtin_amdgcn_mfma_f32_16x16x32_bf16(ones8, pk, sum1, 0, 0, 0);
        }
        __builtin_amdgcn_s_setprio(0);
    };

    // 2-deep register prefetch pipeline: A/B fragment sets, unroll x2
    short8 b0A, b1A, v0A, v1A, b0B, b1B, v0B, v1B;
    {   // prologue: load chunk 0 into A
        const int c = CIDX(0);
        b0A = *(const short8*)(Bl0 + (size_t)c * CI_);
        b1A = *(const short8*)(Bl1 + (size_t)c * CI_);
        v0A = *(const short8*)(Vl0 + (size_t)(c >> 5) * 1024);
        v1A = *(const short8*)(Vl1 + (size_t)(c >> 5) * 1024);
    }
    for (int it = 0; it < 32; it += 2) {
        {   // issue loads for it+1 into B
            const int c = CIDX(it + 1);
            b0B = *(const short8*)(Bl0 + (size_t)c * CI_);
            b1B = *(const short8*)(Bl1 + (size_t)c * CI_);
            v0B = *(const short8*)(Vl0 + (size_t)(c >> 5) * 1024);
            v1B = *(const short8*)(Vl1 + (size_t)(c >> 5) * 1024);
        }
        compute(b0A, b1A, v0A, v1A);
        if (it + 2 < 32) {   // issue loads for it+2 into A
            const int c = CIDX(it + 2);
            b0A = *(const short8*)(Bl0 + (size_t)c * CI_);
            b1A = *(const short8*)(Bl1 + (size_t)c * CI_);
            v0A = *(const short8*)(Vl0 + (size_t)(c >> 5) * 1024);
            v1A = *(const short8*)(Vl1 + (size_t)(c >> 5) * 1024);
        }
        compute(b0B, b1B, v0B, v1B);
    }
    #undef CIDX

    // every lane's sum*[0] = exp-sum partial for its m-row (all rows of the
    // ones-MFMA D are identical); no cross-lane reduce needed.
    const float s0r = sum0[0];
    const float s1r = sum1[0];

    __syncthreads();                                 // E0: enter epilogue
    if (cg >= 2) {                                   // seed buf2[cg-2]
        float* r0p = buf2[cg - 2][rg * 32 + lr];
        float* r1p = buf2[cg - 2][rg * 32 + 16 + lr];
#pragma unroll
        for (int i = 0; i < 4; ++i) {
            r0p[4 * lg + i]      = a00[i];
            r0p[16 + 4 * lg + i] = a01[i];
            r1p[4 * lg + i]      = a10[i];
            r1p[16 + 4 * lg + i] = a11[i];
        }
    }
    if (lane < 16) {
        sums[cg][rg * 32 + lane]      = s0r;
        sums[cg][rg * 32 + 16 + lane] = s1r;
    }
    for (int i = tid; i < C_ * CI_; i += 512) {      // fold output weights
        int co = i >> 5;
        float inv = w_bn[co] * rsqrtf(w_bn[192 + co] + EPS_);
        (&wf2[0][0])[i] = inv * Ww[i];               // flat [co][ci]
    }
    if (tid < C_) {
        float inv = w_bn[tid] * rsqrtf(w_bn[192 + tid] + EPS_);
        bf2v[tid] = inv * Wb[tid] + (w_bn[64 + tid] - w_bn[128 + tid] * inv);
    }
    __syncthreads();                                 // E1
    if (cg < 2) {                                    // add into buf2[cg]
        float* r0p = buf2[cg][rg * 32 + lr];
        float* r1p = buf2[cg][rg * 32 + 16 + lr];
#pragma unroll
        for (int i = 0; i < 4; ++i) {
            r0p[4 * lg + i]      += a00[i];
            r0p[16 + 4 * lg + i] += a01[i];
            r1p[4 * lg + i]      += a10[i];
            r1p[16 + 4 * lg + i] += a11[i];
        }
    }
    __syncthreads();                                 // E2
    {   // combine 2 buffers + 4 sums, normalize -> ybuf (512 thr: 4 elems)
        int m = tid >> 3;
        int ci0 = (tid & 7) * 4;
        float s = (sums[0][m] + sums[1][m]) + (sums[2][m] + sums[3][m]);
        float inv = 1.0f / s;
#pragma unroll
        for (int q = 0; q < 4; ++q) {
            ybuf[m][ci0 + q] = (buf2[0][m][ci0 + q] + buf2[1][m][ci0 + q]) * inv;
        }
    }
    __syncthreads();                                 // E3

    // fused output conv + BN + residual: out[co][m] = x[co][m] + sum_ci wf2*y
    const int m   = tid & 63;
    const int cog = tid >> 6;                        // wave handles co = 8*cog..+7
    float4v yq[8];
#pragma unroll
    for (int q = 0; q < 8; ++q) yq[q] = *(const float4v*)&ybuf[m][q * 4];
    const float* xb2 = (side ? x2 : x1) + (size_t)b * C_ * N_;
    float* ob = out + (size_t)side * (B_ * C_ * N_) + (size_t)b * C_ * N_;
#pragma unroll
    for (int k = 0; k < 8; ++k) {
        const int co = cog * 8 + k;
        float a2 = bf2v[co];
#pragma unroll
        for (int ci = 0; ci < CI_; ++ci) a2 += wf2[co][ci] * yq[ci >> 2][ci & 3];
        ob[(size_t)co * N_ + r0 + m] = xb2[(size_t)co * N_ + r0 + m] + a2;
    }
}

// ---------------------------------------------------------------------------
extern "C" void kernel_launch(void* const* d_in, const int* in_sizes, int n_in,
                              void* d_out, int out_size, void* d_ws, size_t ws_size,
                              hipStream_t stream)
{
    (void)in_sizes; (void)n_in; (void)out_size; (void)ws_size;
    const float* x1   = (const float*)d_in[0];
    const float* x2   = (const float*)d_in[1];
    const float* g_bn = (const float*)d_in[2];
    const float* g_w  = (const float*)d_in[3];
    const float* g_b  = (const float*)d_in[4];
    const float* t_bn = (const float*)d_in[5];
    const float* t_w  = (const float*)d_in[6];
    const float* t_b  = (const float*)d_in[7];
    const float* p_bn = (const float*)d_in[8];
    const float* p_w  = (const float*)d_in[9];
    const float* p_b  = (const float*)d_in[10];
    const float* w_bn = (const float*)d_in[11];
    const float* W_w  = (const float*)d_in[12];
    const float* W_b  = (const float*)d_in[13];
    float* out = (float*)d_out;

    char* ws = (char*)d_ws;
    const size_t MB = 1u << 20;
    short* th_t = (short*)(ws + 0 * MB);             // [B][N][32] bf16 (x log2e)
    short* ph_t = (short*)(ws + 1 * MB);             // [B][N][32] bf16
    short* g1q  = (short*)(ws + 2 * MB);             // [B] paired-chunk V bf16
    short* g2q  = (short*)(ws + 3 * MB);             // [B] paired-chunk V bf16

    proj_kernel<<<dim3(512), dim3(512), 0, stream>>>(
        x1, x2, g_w, g_b, g_bn, t_w, t_b, t_bn, p_w, p_b, p_bn,
        th_t, ph_t, g1q, g2q);

    apply_kernel<<<dim3(512), dim3(512), 0, stream>>>(
        th_t, ph_t, g1q, g2q, x1, x2, W_w, W_b, w_bn, out);
}

// Round 24
// 42.171 us; speedup vs baseline: 3.3110x; 3.3110x over previous
//
#include <hip/hip_runtime.h>
#include <hip/hip_bf16.h>
#include <cstdint>
#include <cstddef>

// Spatiotemporal dual-softmax attention, MI355X (gfx950).
// B=4, C=64, CI=32, N=H*W=4096. Flash-style, never materializes the 4096^2
// energy matrix. Round-24 = round-21 verbatim (best passing kernel,
// 41.92 us). r22 (direct-global, no LDS) and r23 (register prefetch via
// lambda -> accumulator scratch spill, 400MB writes) both lost to this
// structure; locking in the proven best.
//   proj  (512 blk x 512): MFMA projections (r18-proven).
//   apply (512 blk x 512): XCD-aware remap (r20), 8 waves = 2 rg x 4 cg,
//         256-col windows x 16, 2-chunk inner loop, double-buffered LDS,
//         reg-staged issue-early / write-late (T14), one barrier per window.
//         Energy MFMA (swapped operands) -> exp2 (theta pre-scaled by log2e;
//         energies provably << 80, no max subtraction) -> bf16 pack ->
//         K=32 PV MFMA. Row-sums via ones-MFMA; s_setprio(1) around compute.
//         Epilogue: 4-way cg combine, normalize, output conv+BN+residual.

#define B_  4
#define C_  64
#define CI_ 32
#define N_  4096
static constexpr float EPS_   = 1e-5f;
static constexpr float LOG2E_ = 1.4426950408889634f;

typedef __attribute__((ext_vector_type(8))) short  short8;
typedef __attribute__((ext_vector_type(4))) short  short4v;
typedef __attribute__((ext_vector_type(4))) float  float4v;
typedef __attribute__((ext_vector_type(4))) __bf16 bf16x4;
typedef __attribute__((ext_vector_type(8))) __bf16 bf16x8;

__device__ __forceinline__ short f2bf(float f) {
    unsigned u = __float_as_uint(f);
    unsigned r = (u + 0x7fffu + ((u >> 16) & 1u)) >> 16;   // RNE
    return (short)r;
}

// ---------------------------------------------------------------------------
// MFMA projections (r18-proven). side = blk>>8: 0: x1 -> {theta*log2e, g1};
// 1: x2 -> {phi, g2}. theta/phi: [b][n][32] frag layout (scale folded into
// weights+bias); g: [b][32][n] row-major (V layout). 64 n-cols per block.
// 8 waves = set(2) x oTile(2) x nPair(2); each wave: 2 nTiles x 2 K-MFMAs.
// ---------------------------------------------------------------------------
__global__ __launch_bounds__(512) void proj_kernel(
    const float* __restrict__ x1, const float* __restrict__ x2,
    const float* __restrict__ g_w, const float* __restrict__ g_b, const float* __restrict__ g_bn,
    const float* __restrict__ t_w, const float* __restrict__ t_b, const float* __restrict__ t_bn,
    const float* __restrict__ p_w, const float* __restrict__ p_b, const float* __restrict__ p_bn,
    short* __restrict__ th_t, short* __restrict__ ph_t,
    short* __restrict__ g1l, short* __restrict__ g2l)
{
    const int side = blockIdx.x >> 8;
    const int rb   = blockIdx.x & 255;
    const int b    = rb >> 6;
    const int n0   = (rb & 63) * 64;
    const int tid  = threadIdx.x;
    const int wv   = tid >> 6, lane = tid & 63;
    const int lg   = lane >> 4, lr = lane & 15;

    const float* x   = side ? x2   : x1;
    const float* wA  = side ? p_w  : t_w;
    const float* bA  = side ? p_b  : t_b;
    const float* bnA = side ? p_bn : t_bn;
    short* outA      = side ? ph_t : th_t;
    short* outG      = side ? g2l  : g1l;
    const float scaleA = side ? 1.0f : LOG2E_;   // theta carries log2e

    __shared__ short xs_t[64][72];      // 9216 B  X^T: [n][c] bf16 (pad 72)
    __shared__ short wfb[2][32][72];    // 9216 B  [set][o][c] bf16 (pad 72)
    __shared__ float bfold[2][CI_];

    for (int it = 0; it < 4; it++) {                 // fold both weight sets
        int idx = it * 512 + tid;                    // [o][c] flat, 2048
        int o = idx >> 6, c = idx & 63;
        float invA = bnA[c]  * rsqrtf(bnA[192 + c]  + EPS_);
        float invG = g_bn[c] * rsqrtf(g_bn[192 + c] + EPS_);
        wfb[0][o][c] = f2bf(wA[idx]  * invA * scaleA);
        wfb[1][o][c] = f2bf(g_w[idx] * invG);
    }
    if (tid < 2 * CI_) {
        int set = tid >> 5, o = tid & 31;
        const float* bn = set ? g_bn : bnA;
        const float* w  = set ? g_w  : wA;
        const float* bs = set ? g_b  : bA;
        float s = bs[o];
        for (int c = 0; c < C_; c++) {
            float inv = bn[c] * rsqrtf(bn[192 + c] + EPS_);
            s += w[o * C_ + c] * (bn[64 + c] - bn[128 + c] * inv);
        }
        bfold[set][o] = set ? s : s * scaleA;
    }
    const float* xb = x + (size_t)b * C_ * N_ + n0;
    for (int it = 0; it < 2; it++) {                 // stage X^T as bf16
        int idx = it * 512 + tid;                    // 1024 float4 pieces
        int c = idx >> 4, nq = idx & 15;
        float4 xv = *(const float4*)(xb + (size_t)c * N_ + nq * 4);
        xs_t[nq * 4 + 0][c] = f2bf(xv.x);
        xs_t[nq * 4 + 1][c] = f2bf(xv.y);
        xs_t[nq * 4 + 2][c] = f2bf(xv.z);
        xs_t[nq * 4 + 3][c] = f2bf(xv.w);
    }
    __syncthreads();

    const int set = wv & 1;              // 0 = theta/phi, 1 = g
    const int oT  = (wv >> 1) & 1;       // o tile: o = oT*16 + lg*4 + i
    const int nP  = wv >> 2;             // n pair: nTiles {2nP, 2nP+1}

    const float4v zero4 = {0.f, 0.f, 0.f, 0.f};
    // W A-frags (lane: A[row = oT*16+lr][k = c0 + lg*8 + j])
    short8 wf0 = *(const short8*)&wfb[set][oT * 16 + lr][lg * 8];
    short8 wf1 = *(const short8*)&wfb[set][oT * 16 + lr][32 + lg * 8];
    float4v cinit = zero4;
#pragma unroll
    for (int i = 0; i < 4; ++i) cinit[i] = bfold[set][oT * 16 + lg * 4 + i];

#pragma unroll
    for (int t = 0; t < 2; ++t) {
        const int nT = nP * 2 + t;
        // X B-frags (lane: B[k = c0 + lg*8 + j][col = nT*16 + lr])
        short8 xf0 = *(const short8*)&xs_t[nT * 16 + lr][lg * 8];
        short8 xf1 = *(const short8*)&xs_t[nT * 16 + lr][32 + lg * 8];
        float4v d = __builtin_amdgcn_mfma_f32_16x16x32_bf16(wf0, xf0, cinit, 0, 0, 0);
        d = __builtin_amdgcn_mfma_f32_16x16x32_bf16(wf1, xf1, d, 0, 0, 0);
        // d[i] = out[o = oT*16 + lg*4 + i][n = n0 + nT*16 + lr]
        const int n = n0 + nT * 16 + lr;
        if (set == 0) {
            short4v v;
#pragma unroll
            for (int i = 0; i < 4; ++i) v[i] = f2bf(d[i]);
            *(short4v*)(outA + ((size_t)b * N_ + n) * CI_ + oT * 16 + lg * 4) = v;
        } else {
#pragma unroll
            for (int i = 0; i < 4; ++i)
                outG[((size_t)b * CI_ + oT * 16 + lg * 4 + i) * N_ + n] = f2bf(d[i]);
        }
    }
}

// ---------------------------------------------------------------------------
// Apply (fused softmax-sum + PV + output conv + residual).
// XCD-aware decode: g = bid&7 -> (side,b) group pinned to one XCD's L2;
// j = bid>>3 -> r0-block. 8 waves = 2 rg x 4 cg. Per 256-col window, wave
// (rg,cg) computes its 32 m-rows against chunks ch2*128 + cg*32, ch2 = 0,1.
// Double-buffered LDS; reg-staged issue-early / write-late; ONE barrier per
// window. PV + sums via K=32 MFMAs (matched per-lane k-permutation).
// ---------------------------------------------------------------------------
__global__ __launch_bounds__(512, 6) void apply_kernel(
    const short* __restrict__ th, const short* __restrict__ ph,
    const short* __restrict__ g1l, const short* __restrict__ g2l,
    const float* __restrict__ x1, const float* __restrict__ x2,
    const float* __restrict__ Ww, const float* __restrict__ Wb,
    const float* __restrict__ w_bn,
    float* __restrict__ out)
{
    const int bid  = blockIdx.x;
    const int grp  = bid & 7;               // (side,b) group -> XCD affinity
    const int side = grp >> 2;
    const int b    = grp & 3;
    const int r0   = (bid >> 3) * 64;
    const short* A  = side ? th : ph;       // rows = softmax/output dim (m)
    const short* Bm = side ? ph : th;       // cols = reduction dim (n)
    const short* V  = side ? g2l : g1l;
    const int tid = threadIdx.x;
    const int wv = tid >> 6, lane = tid & 63;
    const int cg = wv & 3, rg = wv >> 2;
    const int lg = lane >> 4, lr = lane & 15;

    // main loop: lb [2][256][40]s = 40960 | lv [2][32][264]s = 33792 -> 74752
    __shared__ __align__(16) char smem[74752];
    short (*lb)[256][40] = (short(*)[256][40])smem;
    short (*lv)[32][264] = (short(*)[32][264])(smem + 40960);
    // epilogue overlays (dead vs main loop across barriers)
    float (*buf2)[64][33] = (float(*)[64][33])smem;            // 16896
    float (*sums)[64]     = (float(*)[64])(smem + 16896);      //  1024
    float (*ybuf)[36]     = (float(*)[36])(smem + 17920);      //  9216
    float (*wf2)[CI_]     = (float(*)[CI_])(smem + 27136);     //  8192
    float *bf2v           = (float*)(smem + 35328);            //   256

    const short* Ab = A  + (size_t)b * N_ * CI_;
    const short* Bb = Bm + (size_t)b * N_ * CI_;
    const short* Vb = V  + (size_t)b * CI_ * N_;

    short8 afrag0 = *(const short8*)(Ab + (size_t)(r0 + rg * 32 + lr) * CI_ + lg * 8);
    short8 afrag1 = *(const short8*)(Ab + (size_t)(r0 + rg * 32 + 16 + lr) * CI_ + lg * 8);

    short8 ones8;
#pragma unroll
    for (int i = 0; i < 8; ++i) ones8[i] = (short)0x3F80;    // bf16 1.0

    const float4v zero4 = {0.f, 0.f, 0.f, 0.f};
    float4v a00 = zero4, a01 = zero4;   // t=0: y[ci=4lg+i][m], y[16+4lg+i][m]
    float4v a10 = zero4, a11 = zero4;   // t=1 (m + 16)
    float4v sum0 = zero4, sum1 = zero4; // ones-MFMA sum accumulators

    // staging: 256x32 B (1024 pieces) + 32x256 V (1024 pieces), 2 each/thread
    const int brow0 = tid >> 2,          bpart0 = tid & 3;          // it=0
    const int brow1 = (512 + tid) >> 2,  bpart1 = (512 + tid) & 3;  // it=1
    const int vrow0 = tid >> 5,          vpart0 = tid & 31;
    const int vrow1 = (512 + tid) >> 5,  vpart1 = (512 + tid) & 31;
    const short* gB0 = Bb + (size_t)brow0 * CI_ + bpart0 * 8;
    const short* gB1 = Bb + (size_t)brow1 * CI_ + bpart1 * 8;
    const short* gV0 = Vb + (size_t)vrow0 * N_ + vpart0 * 8;
    const short* gV1 = Vb + (size_t)vrow1 * N_ + vpart1 * 8;

    {   // prologue: stage window 0 into buffer 0
        short8 b0s = *(const short8*)gB0;
        short8 b1s = *(const short8*)gB1;
        short8 v0s = *(const short8*)gV0;
        short8 v1s = *(const short8*)gV1;
        *(short8*)&lb[0][brow0][bpart0 * 8] = b0s;
        *(short8*)&lb[0][brow1][bpart1 * 8] = b1s;
        *(short8*)&lv[0][vrow0][vpart0 * 8] = v0s;
        *(short8*)&lv[0][vrow1][vpart1 * 8] = v1s;
    }
    __syncthreads();

    int cur = 0;
    for (int win = 0; win < 16; ++win) {
        short8 bst0, bst1, vst0, vst1;
        if (win < 15) {                              // issue next window early
            const int s0n = (win + 1) * 256;
            bst0 = *(const short8*)(gB0 + (size_t)s0n * CI_);
            bst1 = *(const short8*)(gB1 + (size_t)s0n * CI_);
            vst0 = *(const short8*)(gV0 + s0n);
            vst1 = *(const short8*)(gV1 + s0n);
        }
        // ---- compute window `win` from buffer `cur` ----
        __builtin_amdgcn_s_setprio(1);
#pragma unroll
        for (int ch2 = 0; ch2 < 2; ++ch2) {
            const int c0 = ch2 * 128 + cg * 32;      // window-local col base
            short8 b0 = *(const short8*)&lb[cur][c0 + lr][lg * 8];
            short8 b1 = *(const short8*)&lb[cur][c0 + 16 + lr][lg * 8];
            short4v v00 = *(const short4v*)&lv[cur][lr][c0 + lg * 4];
            short4v v01 = *(const short4v*)&lv[cur][lr][c0 + 16 + lg * 4];
            short4v v10 = *(const short4v*)&lv[cur][16 + lr][c0 + lg * 4];
            short4v v11 = *(const short4v*)&lv[cur][16 + lr][c0 + 16 + lg * 4];
            // V A-operands with the SAME per-lane k->n permutation as P:
            // j=0..3 -> n=c0+4lg+j, j=4..7 -> n=c0+16+4lg+(j-4)
            short8 vA0 = __builtin_shufflevector(v00, v01, 0, 1, 2, 3, 4, 5, 6, 7);
            short8 vA1 = __builtin_shufflevector(v10, v11, 0, 1, 2, 3, 4, 5, 6, 7);
            {   // t = 0 (m rows r0 + rg*32 + lr)
                float4v e0 = __builtin_amdgcn_mfma_f32_16x16x32_bf16(b0, afrag0, zero4, 0, 0, 0);
                float4v e1 = __builtin_amdgcn_mfma_f32_16x16x32_bf16(b1, afrag0, zero4, 0, 0, 0);
                float p0 = __builtin_amdgcn_exp2f(e0[0]), p1 = __builtin_amdgcn_exp2f(e0[1]);
                float p2 = __builtin_amdgcn_exp2f(e0[2]), p3 = __builtin_amdgcn_exp2f(e0[3]);
                float p4 = __builtin_amdgcn_exp2f(e1[0]), p5 = __builtin_amdgcn_exp2f(e1[1]);
                float p6 = __builtin_amdgcn_exp2f(e1[2]), p7 = __builtin_amdgcn_exp2f(e1[3]);
                bf16x8 q;
                q[0] = (__bf16)p0; q[1] = (__bf16)p1; q[2] = (__bf16)p2; q[3] = (__bf16)p3;
                q[4] = (__bf16)p4; q[5] = (__bf16)p5; q[6] = (__bf16)p6; q[7] = (__bf16)p7;
                short8 pk = __builtin_bit_cast(short8, q);
                a00  = __builtin_amdgcn_mfma_f32_16x16x32_bf16(vA0, pk, a00, 0, 0, 0);
                a01  = __builtin_amdgcn_mfma_f32_16x16x32_bf16(vA1, pk, a01, 0, 0, 0);
                sum0 = __builtin_amdgcn_mfma_f32_16x16x32_bf16(ones8, pk, sum0, 0, 0, 0);
            }
            {   // t = 1 (m rows r0 + rg*32 + 16 + lr)
                float4v e0 = __builtin_amdgcn_mfma_f32_16x16x32_bf16(b0, afrag1, zero4, 0, 0, 0);
                float4v e1 = __builtin_amdgcn_mfma_f32_16x16x32_bf16(b1, afrag1, zero4, 0, 0, 0);
                float p0 = __builtin_amdgcn_exp2f(e0[0]), p1 = __builtin_amdgcn_exp2f(e0[1]);
                float p2 = __builtin_amdgcn_exp2f(e0[2]), p3 = __builtin_amdgcn_exp2f(e0[3]);
                float p4 = __builtin_amdgcn_exp2f(e1[0]), p5 = __builtin_amdgcn_exp2f(e1[1]);
                float p6 = __builtin_amdgcn_exp2f(e1[2]), p7 = __builtin_amdgcn_exp2f(e1[3]);
                bf16x8 q;
                q[0] = (__bf16)p0; q[1] = (__bf16)p1; q[2] = (__bf16)p2; q[3] = (__bf16)p3;
                q[4] = (__bf16)p4; q[5] = (__bf16)p5; q[6] = (__bf16)p6; q[7] = (__bf16)p7;
                short8 pk = __builtin_bit_cast(short8, q);
                a10  = __builtin_amdgcn_mfma_f32_16x16x32_bf16(vA0, pk, a10, 0, 0, 0);
                a11  = __builtin_amdgcn_mfma_f32_16x16x32_bf16(vA1, pk, a11, 0, 0, 0);
                sum1 = __builtin_amdgcn_mfma_f32_16x16x32_bf16(ones8, pk, sum1, 0, 0, 0);
            }
        }
        __builtin_amdgcn_s_setprio(0);
        if (win < 15) {                              // write-late into other buf
            *(short8*)&lb[cur ^ 1][brow0][bpart0 * 8] = bst0;
            *(short8*)&lb[cur ^ 1][brow1][bpart1 * 8] = bst1;
            *(short8*)&lv[cur ^ 1][vrow0][vpart0 * 8] = vst0;
            *(short8*)&lv[cur ^ 1][vrow1][vpart1 * 8] = vst1;
        }
        __syncthreads();                             // one barrier per window
        cur ^= 1;
    }

    // every lane's sum*[0] = exp-sum partial for its m-row (all rows of the
    // ones-MFMA D are identical); no cross-lane reduce needed.
    const float s0r = sum0[0];
    const float s1r = sum1[0];

    // (last barrier of the loop separates main-loop LDS use from overlays)
    if (cg >= 2) {                                   // seed buf2[cg-2]
        float* r0p = buf2[cg - 2][rg * 32 + lr];
        float* r1p = buf2[cg - 2][rg * 32 + 16 + lr];
#pragma unroll
        for (int i = 0; i < 4; ++i) {
            r0p[4 * lg + i]      = a00[i];
            r0p[16 + 4 * lg + i] = a01[i];
            r1p[4 * lg + i]      = a10[i];
            r1p[16 + 4 * lg + i] = a11[i];
        }
    }
    if (lane < 16) {
        sums[cg][rg * 32 + lane]      = s0r;
        sums[cg][rg * 32 + 16 + lane] = s1r;
    }
    for (int i = tid; i < C_ * CI_; i += 512) {      // fold output weights
        int co = i >> 5;
        float inv = w_bn[co] * rsqrtf(w_bn[192 + co] + EPS_);
        (&wf2[0][0])[i] = inv * Ww[i];               // flat [co][ci]
    }
    if (tid < C_) {
        float inv = w_bn[tid] * rsqrtf(w_bn[192 + tid] + EPS_);
        bf2v[tid] = inv * Wb[tid] + (w_bn[64 + tid] - w_bn[128 + tid] * inv);
    }
    __syncthreads();                                 // E1
    if (cg < 2) {                                    // add into buf2[cg]
        float* r0p = buf2[cg][rg * 32 + lr];
        float* r1p = buf2[cg][rg * 32 + 16 + lr];
#pragma unroll
        for (int i = 0; i < 4; ++i) {
            r0p[4 * lg + i]      += a00[i];
            r0p[16 + 4 * lg + i] += a01[i];
            r1p[4 * lg + i]      += a10[i];
            r1p[16 + 4 * lg + i] += a11[i];
        }
    }
    __syncthreads();                                 // E2
    {   // combine 2 buffers + 4 sums, normalize -> ybuf (512 thr: 4 elems)
        int m = tid >> 3;
        int ci0 = (tid & 7) * 4;
        float s = (sums[0][m] + sums[1][m]) + (sums[2][m] + sums[3][m]);
        float inv = 1.0f / s;
#pragma unroll
        for (int q = 0; q < 4; ++q) {
            ybuf[m][ci0 + q] = (buf2[0][m][ci0 + q] + buf2[1][m][ci0 + q]) * inv;
        }
    }
    __syncthreads();                                 // E3

    // fused output conv + BN + residual: out[co][m] = x[co][m] + sum_ci wf2*y
    const int m   = tid & 63;
    const int cog = tid >> 6;                        // wave handles co = 8*cog..+7
    float4v yq[8];
#pragma unroll
    for (int q = 0; q < 8; ++q) yq[q] = *(const float4v*)&ybuf[m][q * 4];
    const float* xb2 = (side ? x2 : x1) + (size_t)b * C_ * N_;
    float* ob = out + (size_t)side * (B_ * C_ * N_) + (size_t)b * C_ * N_;
#pragma unroll
    for (int k = 0; k < 8; ++k) {
        const int co = cog * 8 + k;
        float a2 = bf2v[co];
#pragma unroll
        for (int ci = 0; ci < CI_; ++ci) a2 += wf2[co][ci] * yq[ci >> 2][ci & 3];
        ob[(size_t)co * N_ + r0 + m] = xb2[(size_t)co * N_ + r0 + m] + a2;
    }
}

// ---------------------------------------------------------------------------
extern "C" void kernel_launch(void* const* d_in, const int* in_sizes, int n_in,
                              void* d_out, int out_size, void* d_ws, size_t ws_size,
                              hipStream_t stream)
{
    (void)in_sizes; (void)n_in; (void)out_size; (void)ws_size;
    const float* x1   = (const float*)d_in[0];
    const float* x2   = (const float*)d_in[1];
    const float* g_bn = (const float*)d_in[2];
    const float* g_w  = (const float*)d_in[3];
    const float* g_b  = (const float*)d_in[4];
    const float* t_bn = (const float*)d_in[5];
    const float* t_w  = (const float*)d_in[6];
    const float* t_b  = (const float*)d_in[7];
    const float* p_bn = (const float*)d_in[8];
    const float* p_w  = (const float*)d_in[9];
    const float* p_b  = (const float*)d_in[10];
    const float* w_bn = (const float*)d_in[11];
    const float* W_w  = (const float*)d_in[12];
    const float* W_b  = (const float*)d_in[13];
    float* out = (float*)d_out;

    char* ws = (char*)d_ws;
    const size_t MB = 1u << 20;
    short* th_t = (short*)(ws + 0 * MB);             // [B][N][32] bf16 (x log2e)
    short* ph_t = (short*)(ws + 1 * MB);             // [B][N][32] bf16
    short* g1l  = (short*)(ws + 2 * MB);             // [B][32][N] bf16
    short* g2l  = (short*)(ws + 3 * MB);             // [B][32][N] bf16

    proj_kernel<<<dim3(512), dim3(512), 0, stream>>>(
        x1, x2, g_w, g_b, g_bn, t_w, t_b, t_bn, p_w, p_b, p_bn,
        th_t, ph_t, g1l, g2l);

    apply_kernel<<<dim3(512), dim3(512), 0, stream>>>(
        th_t, ph_t, g1l, g2l, x1, x2, W_w, W_b, w_bn, out);
}